// Round 6
// baseline (62.926 us; speedup 1.0000x reference)
//
#include <hip/hip_runtime.h>
#include <hip/hip_bf16.h>

// PWL monotone interpolation, N=2097152, C=16, B=32. Single fused kernel.
// Each block redundantly computes params (sort/cumsum/slopes) in LDS, then:
// search levels 1-3 in registers (28 VGPR), levels 4-5 via ONE ds_read_b128
// (xs[pos..pos+3], pos%4==0) + 2 register compares, then ONE ds_read_b64 of
// interleaved (a,b). Bank-rotated layouts. 256thr x 2048 blocks = 8/CU.

#define C_CH 16
#define B_KN 32

typedef float f4v __attribute__((ext_vector_type(4)));

__global__ __launch_bounds__(256) void pwl_fused_kernel(
    const float4* __restrict__ x, float4* __restrict__ out,
    const float* __restrict__ xp, const float* __restrict__ y0,
    const float* __restrict__ dy, int n4) {
    __shared__ float  s_raw[C_CH][B_KN];
    __shared__ float  s_xs[C_CH][B_KN];
    __shared__ float  s_ys[C_CH][B_KN];
    __shared__ float  s_x4[C_CH * B_KN];    // xs rotated: word c*32 + ((k+4c)&31)
    __shared__ float2 s_ab[C_CH * B_KN];    // (a,b) rotated: idx  c*32 + ((s+c)&31)

    int t = threadIdx.x;
    // ---- fused setup: 2 (c,k) pairs per thread ----
#pragma unroll
    for (int p = t; p < 512; p += 256) s_raw[p >> 5][p & 31] = xp[p];
    __syncthreads();
#pragma unroll
    for (int p = t; p < 512; p += 256) {
        int c = p >> 5, k = p & 31;
        float v = s_raw[c][k];
        int rank = 0;
#pragma unroll
        for (int j = 0; j < B_KN; ++j) {
            float u = s_raw[c][j];
            rank += (u < v || (u == v && j < k)) ? 1 : 0;
        }
        s_xs[c][rank] = v;
        float acc = y0[c];
        for (int j = 0; j < k; ++j) acc += fabsf(dy[c * (B_KN - 1) + j]);
        s_ys[c][k] = acc;
    }
    __syncthreads();
#pragma unroll
    for (int p = t; p < 512; p += 256) {
        int c = p >> 5, k = p & 31;
        float xk = s_xs[c][k];
        s_x4[c * 32 + ((k + 4 * c) & 31)] = xk;
        float a = 0.0f, b = 0.0f;
        if (k < B_KN - 1) {
            float ya = s_ys[c][k], yb = s_ys[c][k + 1];
            a = (yb - ya) / (s_xs[c][k + 1] - xk);
            b = ya - a * xk;
        }
        s_ab[c * 32 + ((k + c) & 31)] = make_float2(a, b);
    }
    // register search levels for this thread's 4 channels
    int c0 = (t & 3) << 2;
    float v15[4], v7[4], v23[4], v3[4], v11[4], v19[4], v27[4];
    __syncthreads();
#pragma unroll
    for (int j = 0; j < 4; ++j) {
        const float* xs = s_xs[c0 + j];
        v15[j] = xs[15];
        v7[j]  = xs[7];
        v23[j] = xs[23];
        v3[j]  = xs[3];
        v11[j] = xs[11];
        v19[j] = xs[19];
        v27[j] = xs[27];
    }

    const f4v* x4t = (const f4v*)s_x4;
    int tid = blockIdx.x * 256 + t;
    int total = gridDim.x * 256;

    for (int i = tid; i < n4; i += 2 * total) {
        int i1 = i + total;
        float4 v0 = x[i];
        float4 v1 = (i1 < n4) ? x[i1] : v0;
        float xv[8] = {v0.x, v0.y, v0.z, v0.w, v1.x, v1.y, v1.z, v1.w};
        float rr[8];
#pragma unroll
        for (int u = 0; u < 8; ++u) {
            int j = u & 3;
            int c = c0 + j;
            float xq = xv[u];
            bool b16 = (v15[j] < xq);
            float l2v = b16 ? v23[j] : v7[j];
            bool b8 = (l2v < xq);
            float l3a = b16 ? v19[j] : v3[j];
            float l3b = b16 ? v27[j] : v11[j];
            float l3v = b8 ? l3b : l3a;
            bool b4 = (l3v < xq);
            int pos = (b16 ? 16 : 0) + (b8 ? 8 : 0) + (b4 ? 4 : 0);
            // levels 4-5: one b128 read of xs[pos..pos+3] (rotation keeps quads intact)
            f4v w = x4t[c * 8 + (((pos + 4 * c) & 31) >> 2)];
            bool b2 = (w.y < xq);
            pos += b2 ? 2 : 0;
            float wf = b2 ? w.z : w.x;
            pos += (wf < xq) ? 1 : 0;
            int seg = pos < 2 ? 0 : (pos > 31 ? 30 : pos - 1);  // clip(pos,1,31)-1
            float2 ab = s_ab[c * 32 + ((seg + c) & 31)];
            rr[u] = fmaf(ab.x, xq, ab.y);
        }
        f4v r0 = {rr[0], rr[1], rr[2], rr[3]};
        __builtin_nontemporal_store(r0, (f4v*)&out[i]);
        if (i1 < n4) {
            f4v r1 = {rr[4], rr[5], rr[6], rr[7]};
            __builtin_nontemporal_store(r1, (f4v*)&out[i1]);
        }
    }
}

extern "C" void kernel_launch(void* const* d_in, const int* in_sizes, int n_in,
                              void* d_out, int out_size, void* d_ws, size_t ws_size,
                              hipStream_t stream) {
    const float* x  = (const float*)d_in[0];
    const float* xp = (const float*)d_in[1];
    const float* y0 = (const float*)d_in[2];
    const float* dy = (const float*)d_in[3];
    float* out = (float*)d_out;

    int n4 = in_sizes[0] / 4;  // 8388608
    pwl_fused_kernel<<<2048, 256, 0, stream>>>((const float4*)x, (float4*)out,
                                               xp, y0, dy, n4);
}

// Round 7
// 56.165 us; speedup vs baseline: 1.1204x; 1.1204x over previous
//
#include <hip/hip_runtime.h>
#include <hip/hip_bf16.h>

// PWL monotone interpolation, N=2097152, C=16, B=32.
// R1 structure + register search levels 1-3 + 2-deep pipeline + nt stores.
// LDS ops/elem: 2 search reads + a + b = 4 (stride-33 arrays, ~2-way banks).

#define C_CH 16
#define B_KN 32

typedef float f4v __attribute__((ext_vector_type(4)));

// ws float layout: [0..511]=xs(c*32+k), [512..1023]=a(c*32+s), [1024..1535]=b

// ---------------- setup: sort knots, cumsum ys, per-segment a,b ----------------
__global__ __launch_bounds__(512) void pwl_setup_kernel(
    const float* __restrict__ xp, const float* __restrict__ y0,
    const float* __restrict__ dy, float* __restrict__ ws) {
    __shared__ float s_x[C_CH][B_KN];
    __shared__ float s_xs[C_CH][B_KN];
    __shared__ float s_ys[C_CH][B_KN];
    int t = threadIdx.x;
    int c = t >> 5;
    int k = t & 31;
    float v = xp[c * B_KN + k];
    s_x[c][k] = v;
    __syncthreads();
    int rank = 0;
#pragma unroll
    for (int j = 0; j < B_KN; ++j) {
        float u = s_x[c][j];
        rank += (u < v || (u == v && j < k)) ? 1 : 0;
    }
    s_xs[c][rank] = v;
    float acc = y0[c];
    for (int j = 0; j < k; ++j) acc += fabsf(dy[c * (B_KN - 1) + j]);
    s_ys[c][k] = acc;
    __syncthreads();
    ws[c * B_KN + k] = s_xs[c][k];
    if (k < B_KN - 1) {
        float x0 = s_xs[c][k], x1 = s_xs[c][k + 1];
        float ya = s_ys[c][k], yb = s_ys[c][k + 1];
        float a = (yb - ya) / (x1 - x0);
        float b = ya - a * x0;
        ws[512 + c * B_KN + k]  = a;
        ws[1024 + c * B_KN + k] = b;
    } else {
        ws[512 + c * B_KN + k]  = 0.0f;
        ws[1024 + c * B_KN + k] = 0.0f;
    }
}

// ---------------- main ----------------
__global__ __launch_bounds__(256) void pwl_main_kernel(
    const float4* __restrict__ x, float4* __restrict__ out,
    const float* __restrict__ ws, int n4) {
    __shared__ float s_xs[C_CH][B_KN + 1];   // stride 33: bank = (c+idx)%32
    __shared__ float s_a[C_CH][B_KN + 1];
    __shared__ float s_b[C_CH][B_KN + 1];
    int t = threadIdx.x;
    for (int p = t; p < C_CH * B_KN; p += 256) {
        int c = p >> 5, k = p & 31;
        s_xs[c][k] = ws[p];
        s_a[c][k]  = ws[512 + p];
        s_b[c][k]  = ws[1024 + p];
    }
    // register search levels 1-3 for this thread's 4 channels (from global, L1/L2)
    int c0 = (t & 3) << 2;
    float v15[4], v7[4], v23[4], v3[4], v11[4], v19[4], v27[4];
#pragma unroll
    for (int j = 0; j < 4; ++j) {
        const float* xs = ws + (c0 + j) * B_KN;
        v15[j] = xs[15];
        v7[j]  = xs[7];
        v23[j] = xs[23];
        v3[j]  = xs[3];
        v11[j] = xs[11];
        v19[j] = xs[19];
        v27[j] = xs[27];
    }
    __syncthreads();

    int tid = blockIdx.x * 256 + t;
    int total = gridDim.x * 256;

    for (int i = tid; i < n4; i += 2 * total) {
        int i1 = i + total;
        float4 v0 = x[i];
        float4 v1 = (i1 < n4) ? x[i1] : v0;
        float xv[8] = {v0.x, v0.y, v0.z, v0.w, v1.x, v1.y, v1.z, v1.w};
        float rr[8];
#pragma unroll
        for (int u = 0; u < 8; ++u) {
            int j = u & 3;
            int c = c0 + j;
            float xq = xv[u];
            // levels 1-3: registers (cndmask chains)
            bool b16 = (v15[j] < xq);
            float l2v = b16 ? v23[j] : v7[j];
            bool b8 = (l2v < xq);
            float l3a = b16 ? v19[j] : v3[j];
            float l3b = b16 ? v27[j] : v11[j];
            float l3v = b8 ? l3b : l3a;
            bool b4 = (l3v < xq);
            int pos = (b16 ? 16 : 0) + (b8 ? 8 : 0) + (b4 ? 4 : 0);
            // levels 4-5: LDS (stride-33, ~2-way)
            pos += (s_xs[c][pos + 1] < xq) ? 2 : 0;
            pos += (s_xs[c][pos] < xq) ? 1 : 0;
            int seg = pos < 2 ? 0 : (pos > 31 ? 30 : pos - 1);  // clip(pos,1,31)-1
            rr[u] = fmaf(s_a[c][seg], xq, s_b[c][seg]);
        }
        f4v r0 = {rr[0], rr[1], rr[2], rr[3]};
        __builtin_nontemporal_store(r0, (f4v*)&out[i]);
        if (i1 < n4) {
            f4v r1 = {rr[4], rr[5], rr[6], rr[7]};
            __builtin_nontemporal_store(r1, (f4v*)&out[i1]);
        }
    }
}

extern "C" void kernel_launch(void* const* d_in, const int* in_sizes, int n_in,
                              void* d_out, int out_size, void* d_ws, size_t ws_size,
                              hipStream_t stream) {
    const float* x  = (const float*)d_in[0];
    const float* xp = (const float*)d_in[1];
    const float* y0 = (const float*)d_in[2];
    const float* dy = (const float*)d_in[3];
    float* out = (float*)d_out;
    float* ws  = (float*)d_ws;

    pwl_setup_kernel<<<1, 512, 0, stream>>>(xp, y0, dy, ws);

    int n4 = in_sizes[0] / 4;  // 8388608
    pwl_main_kernel<<<2048, 256, 0, stream>>>((const float4*)x, (float4*)out, ws, n4);
}

// Round 8
// 52.228 us; speedup vs baseline: 1.2048x; 1.0754x over previous
//
#include <hip/hip_runtime.h>
#include <hip/hip_bf16.h>

// PWL monotone interpolation, N=2097152, C=16, B=32.
// R1 structure exactly, with ONE change: all LDS tables stored under the
// bit-rotation permutation R(k)=((k<<2)|(k>>3))&31 (stride 33 kept), which
// spreads the stride-4-correlated data-dependent gathers across all banks
// (bank = c + R(idx), channel-group bank-sets disjoint by enumeration).

#define C_CH 16
#define B_KN 32

#define ROT(k) ((((k) << 2) | ((k) >> 3)) & 31)

// ws float layout: [0..511]=xs(c*32+k), [512..1023]=a(c*32+s), [1024..1535]=b

// ---------------- setup: sort knots, cumsum ys, per-segment a,b ----------------
__global__ __launch_bounds__(512) void pwl_setup_kernel(
    const float* __restrict__ xp, const float* __restrict__ y0,
    const float* __restrict__ dy, float* __restrict__ ws) {
    __shared__ float s_x[C_CH][B_KN];
    __shared__ float s_xs[C_CH][B_KN];
    __shared__ float s_ys[C_CH][B_KN];
    int t = threadIdx.x;
    int c = t >> 5;
    int k = t & 31;
    float v = xp[c * B_KN + k];
    s_x[c][k] = v;
    __syncthreads();
    int rank = 0;
#pragma unroll
    for (int j = 0; j < B_KN; ++j) {
        float u = s_x[c][j];
        rank += (u < v || (u == v && j < k)) ? 1 : 0;
    }
    s_xs[c][rank] = v;
    float acc = y0[c];
    for (int j = 0; j < k; ++j) acc += fabsf(dy[c * (B_KN - 1) + j]);
    s_ys[c][k] = acc;
    __syncthreads();
    ws[c * B_KN + k] = s_xs[c][k];
    if (k < B_KN - 1) {
        float x0 = s_xs[c][k], x1 = s_xs[c][k + 1];
        float ya = s_ys[c][k], yb = s_ys[c][k + 1];
        float a = (yb - ya) / (x1 - x0);
        float b = ya - a * x0;
        ws[512 + c * B_KN + k]  = a;
        ws[1024 + c * B_KN + k] = b;
    } else {
        ws[512 + c * B_KN + k]  = 0.0f;
        ws[1024 + c * B_KN + k] = 0.0f;
    }
}

// ---------------- main: R1 loop, rotl2-permuted LDS layout ----------------
__global__ __launch_bounds__(256) void pwl_main_kernel(
    const float4* __restrict__ x, float4* __restrict__ out,
    const float* __restrict__ ws, int n4) {
    __shared__ float s_xs[C_CH][B_KN + 1];   // entry k stored at [c][ROT(k)]
    __shared__ float s_a[C_CH][B_KN + 1];
    __shared__ float s_b[C_CH][B_KN + 1];
    for (int i = threadIdx.x; i < C_CH * B_KN; i += 256) {
        int c = i >> 5, k = i & 31;
        int rk = ROT(k);
        s_xs[c][rk] = ws[i];
        s_a[c][rk]  = ws[512 + i];
        s_b[c][rk]  = ws[1024 + i];
    }
    __syncthreads();

    int tid = blockIdx.x * 256 + threadIdx.x;
    int stride = gridDim.x * 256;
    int c0 = (threadIdx.x & 3) << 2;   // i&3 constant per thread (stride % 4 == 0)
    for (int i = tid; i < n4; i += stride) {
        float4 v = x[i];
        float xv[4] = {v.x, v.y, v.z, v.w};
        float r[4];
#pragma unroll
        for (int j = 0; j < 4; ++j) {
            int c = c0 + j;
            float xq = xv[j];
            const float* xs = s_xs[c];
            // branchless lower_bound: pos = min(#{xs[i] < xq}, 31)
            int pos = 0;
#pragma unroll
            for (int s = 16; s >= 1; s >>= 1) {
                int idx = pos + s - 1;
                pos += (xs[ROT(idx)] < xq) ? s : 0;
            }
            int seg = (pos > 1 ? pos : 1) - 1;  // clip(searchsorted,1,31)-1
            seg = seg > 30 ? 30 : seg;
            int rseg = ROT(seg);
            r[j] = fmaf(s_a[c][rseg], xq, s_b[c][rseg]);
        }
        out[i] = make_float4(r[0], r[1], r[2], r[3]);
    }
}

extern "C" void kernel_launch(void* const* d_in, const int* in_sizes, int n_in,
                              void* d_out, int out_size, void* d_ws, size_t ws_size,
                              hipStream_t stream) {
    const float* x  = (const float*)d_in[0];
    const float* xp = (const float*)d_in[1];
    const float* y0 = (const float*)d_in[2];
    const float* dy = (const float*)d_in[3];
    float* out = (float*)d_out;
    float* ws  = (float*)d_ws;

    pwl_setup_kernel<<<1, 512, 0, stream>>>(xp, y0, dy, ws);

    int n4 = in_sizes[0] / 4;  // 8388608
    int blocks = (n4 + 255) / 256;
    if (blocks > 2048) blocks = 2048;
    pwl_main_kernel<<<blocks, 256, 0, stream>>>((const float4*)x, (float4*)out, ws, n4);
}